// Round 5
// baseline (119.055 us; speedup 1.0000x reference)
//
#include <hip/hip_runtime.h>
#include <hip/hip_bf16.h>

// Median blur 3x3 (kornia semantics) + fused mask copy.
// median commutes with monotone affine maps: 2*median((v+1)/2)-1 == median(v)
// with pad sentinel -1.0 (maps to reference's zero-pad in (v+1)/2 space).
//
// R5 = R4 with native ext_vector_type for nontemporal builtins
// (__builtin_nontemporal_* rejects HIP_vector_type class pointers):
//  - mask-copy blocks interleaved (b%4==3) instead of tail -> overlap streams
//  - v_med3_f32 via __builtin_amdgcn_fmed3f; min3/max3 chain -> v_min3/v_max3
//  - streaming 3-row ring instead of t[6][6] -> lower VGPR pressure
//  - nontemporal stores (output never re-read; don't thrash L2 halo rows)

#define W 512
#define H 512
#define PLANE (W * H)                 // 262144
#define NPLANES 48                    // 16 * 3
#define IMG_ELEMS (PLANE * NPLANES)   // 12582912
#define MASK_ELEMS (PLANE * 16)       // 4194304
#define MED_BLOCKS 3072               // NPLANES * (H/4) * (W/4) / 256
#define TOTAL_BLOCKS 4096             // 3072 med + 1024 mask, interleaved 3:1

typedef float nfloat4 __attribute__((ext_vector_type(4)));

__device__ __forceinline__ float med3(float a, float b, float c) {
    return __builtin_amdgcn_fmed3f(a, b, c);
}
__device__ __forceinline__ float min3(float a, float b, float c) {
    return fminf(fminf(a, b), c);     // -> v_min3_f32
}
__device__ __forceinline__ float max3(float a, float b, float c) {
    return fmaxf(fmaxf(a, b), c);     // -> v_max3_f32
}

__global__ __launch_bounds__(256) void fused_kernel(
        const float* __restrict__ img, const float* __restrict__ mask,
        float* __restrict__ out) {
    unsigned b = blockIdx.x;

    if ((b & 3u) == 3u) {
        // ---- mask copy: 1/4 of blocks, interleaved through the dispatch ----
        int m = b >> 2;                               // 0..1023
        int i = m * 1024 + threadIdx.x;               // base float4 index
        const nfloat4* src = (const nfloat4*)mask;
        nfloat4* dst = (nfloat4*)(out + IMG_ELEMS);
        #pragma unroll
        for (int k = 0; k < 4; ++k) {
            nfloat4 v = __builtin_nontemporal_load(src + i + k * 256);
            __builtin_nontemporal_store(v, dst + i + k * 256);
        }
        return;
    }

    // ---- median path: med block id d = b - (b>>2); [plane 48][rowblk 128][xseg 128]
    int d = (int)(b - (b >> 2));
    int idx = d * 256 + threadIdx.x;
    int xseg = idx & 127;
    int rb = (idx >> 7) & 127;
    int p = idx >> 14;              // 0..47
    int x0 = xseg << 2;             // 0..508
    int y0 = rb << 2;               // 0..508

    const float* plane = img + (size_t)p * PLANE;
    float* outp = out + (size_t)p * PLANE + y0 * W + x0;

    // Streaming over 6 input rows (y0-1 .. y0+4), ring of 3 sorted rows.
    // rl/rm/rh[s][k] = sorted {t[k], t[k+1], t[k+2]} for ring slot s.
    float rl[3][4], rm[3][4], rh[3][4];

    #pragma unroll
    for (int r = 0; r < 6; ++r) {
        int yy = y0 + r - 1;
        float t0, t1, t2, t3, t4, t5;
        if (yy >= 0 && yy < H) {          // wave-uniform (rb uniform in wave)
            const float* row = plane + yy * W;
            nfloat4 c = *(const nfloat4*)(row + x0);   // aligned
            t1 = c.x; t2 = c.y; t3 = c.z; t4 = c.w;
            t0 = (x0 > 0)     ? row[x0 - 1] : -1.0f;
            t5 = (x0 + 4 < W) ? row[x0 + 4] : -1.0f;
        } else {
            t0 = t1 = t2 = t3 = t4 = t5 = -1.0f;
        }

        int s = r % 3;
        rl[s][0] = min3(t0, t1, t2); rm[s][0] = med3(t0, t1, t2); rh[s][0] = max3(t0, t1, t2);
        rl[s][1] = min3(t1, t2, t3); rm[s][1] = med3(t1, t2, t3); rh[s][1] = max3(t1, t2, t3);
        rl[s][2] = min3(t2, t3, t4); rm[s][2] = med3(t2, t3, t4); rh[s][2] = max3(t2, t3, t4);
        rl[s][3] = min3(t3, t4, t5); rm[s][3] = med3(t3, t4, t5); rh[s][3] = max3(t3, t4, t5);

        if (r >= 2) {
            int oy = r - 2;
            int s0 = oy % 3, s1 = (oy + 1) % 3, s2 = (oy + 2) % 3;
            nfloat4 o;
            #pragma unroll
            for (int k = 0; k < 4; ++k) {
                float mx = max3(rl[s0][k], rl[s1][k], rl[s2][k]);
                float md = med3(rm[s0][k], rm[s1][k], rm[s2][k]);
                float mn = min3(rh[s0][k], rh[s1][k], rh[s2][k]);
                o[k] = med3(mx, md, mn);
            }
            __builtin_nontemporal_store(o, (nfloat4*)(outp + oy * W));
        }
    }
}

extern "C" void kernel_launch(void* const* d_in, const int* in_sizes, int n_in,
                              void* d_out, int out_size, void* d_ws, size_t ws_size,
                              hipStream_t stream) {
    const float* img  = (const float*)d_in[0];
    const float* mask = (const float*)d_in[1];
    float* out = (float*)d_out;

    fused_kernel<<<TOTAL_BLOCKS, 256, 0, stream>>>(img, mask, out);
}